// Round 1
// baseline (76.414 us; speedup 1.0000x reference)
//
#include <hip/hip_runtime.h>
#include <math.h>

// LFQ: D=20 bits, K=2^20, TEMP=0.005, x:[2,128,20] fp32, 256 tokens.
// Factorized softmax over the +-1 hypercube codebook:
//   p_t(k) = prod_j sigma(2 x_tj / T)^(b_kj) * sigma(-2 x_tj / T)^(1-b_kj)
// entropy_t = sum_j H(sigma(400 x_tj));  mean_probs = (1/256) Hi^T Lo with
// 10/10 bit split; mean_entro = -sum_k M_k log(M_k + 1e-10).

#define LFQ_D 20
#define NTOK 256
#define NQ (NTOK * LFQ_D)   // 5120

// ws layout (bytes):
//   Hi[t][a] float : 256*1024*4 = 1 MB   @ 0
//   Lo[t][b] float : 1 MB                @ 1 MB
//   entPart[256] double                  @ 2 MB
//   comPart[256] double                  @ 2 MB + 2048
//   mePart [256] double                  @ 2 MB + 4096

__global__ __launch_bounds__(64) void lfq_k1_pertoken(
    const float* __restrict__ x, float* __restrict__ out,
    float* __restrict__ Hi, float* __restrict__ Lo,
    double* __restrict__ entPart, double* __restrict__ comPart) {
  const int t = blockIdx.x;
  const int tid = threadIdx.x;
  __shared__ float P1[LFQ_D], P0[LFQ_D];
  __shared__ double hbuf[LFQ_D], cbuf[LFQ_D];
  if (tid < LFQ_D) {
    float xv = x[t * LFQ_D + tid];
    double z = 400.0 * (double)xv;         // 2x/TEMP
    double az = fabs(z);
    double e = exp(-az);                   // underflows to 0 for big |z| -> exact
    double s = e / (1.0 + e);              // sigma(-|z|)
    double p1 = (z >= 0.0) ? (1.0 - s) : s; // P(bit=+1)
    P1[tid] = (float)p1;
    P0[tid] = (float)(1.0 - p1);
    // stable binary entropy in nats: H = log1p(e) + |z| * sigma(-|z|)
    hbuf[tid] = log1p(e) + az * s;
    float qv = (xv > 0.0f) ? 1.0f : -1.0f;
    out[t * LFQ_D + tid] = qv;             // straight-through forward value
    double dx = (double)xv - (double)qv;
    cbuf[tid] = dx * dx;
  }
  __syncthreads();
  if (tid == 0) {
    double hs = 0.0, cs = 0.0;
    for (int j = 0; j < LFQ_D; ++j) { hs += hbuf[j]; cs += cbuf[j]; }
    entPart[t] = hs;
    comPart[t] = cs;
  }
  // Hi over high 10 bits (x columns j=0..9): bit_j = (a >> (9-j)) & 1
  for (int a = tid; a < 1024; a += 64) {
    float prod = 1.0f;
#pragma unroll
    for (int j = 0; j < 10; ++j) {
      int bit = (a >> (9 - j)) & 1;
      prod *= bit ? P1[j] : P0[j];
    }
    Hi[t * 1024 + a] = prod;
  }
  // Lo over low 10 bits (x columns j=10..19)
  for (int b = tid; b < 1024; b += 64) {
    float prod = 1.0f;
#pragma unroll
    for (int m = 0; m < 10; ++m) {
      int bit = (b >> (9 - m)) & 1;
      prod *= bit ? P1[10 + m] : P0[10 + m];
    }
    Lo[t * 1024 + b] = prod;
  }
}

// M[a][b] = (1/256) sum_t Hi[t][a] * Lo[t][b];  accumulate -M log(M+1e-10).
// Grid 16x16, block 256 (tx=tid&15 -> a, ty=tid>>4 -> b), 4x4 per thread.
__global__ __launch_bounds__(256) void lfq_k2_meanentro(
    const float* __restrict__ Hi, const float* __restrict__ Lo,
    double* __restrict__ mePart) {
  __shared__ float sHi[32][64];
  __shared__ float sLo[32][64];
  const int tid = threadIdx.x;
  const int tx = tid & 15, ty = tid >> 4;
  const int a0 = blockIdx.x * 64, b0 = blockIdx.y * 64;
  float acc[4][4];
#pragma unroll
  for (int i = 0; i < 4; ++i)
#pragma unroll
    for (int j = 0; j < 4; ++j) acc[i][j] = 0.0f;

  for (int c = 0; c < 8; ++c) {  // t-chunks of 32
#pragma unroll
    for (int k = 0; k < 8; ++k) {
      int e = tid + k * 256;
      int tl = e >> 6, i = e & 63;
      sHi[tl][i] = Hi[(c * 32 + tl) * 1024 + a0 + i];
      sLo[tl][i] = Lo[(c * 32 + tl) * 1024 + b0 + i];
    }
    __syncthreads();
#pragma unroll
    for (int tt = 0; tt < 32; ++tt) {
      float4 ha = *(const float4*)&sHi[tt][tx * 4];
      float4 lb = *(const float4*)&sLo[tt][ty * 4];
      float hav[4] = {ha.x, ha.y, ha.z, ha.w};
      float lbv[4] = {lb.x, lb.y, lb.z, lb.w};
#pragma unroll
      for (int i = 0; i < 4; ++i)
#pragma unroll
        for (int j = 0; j < 4; ++j)
          acc[i][j] = fmaf(hav[i], lbv[j], acc[i][j]);
    }
    __syncthreads();
  }

  double tsum = 0.0;
#pragma unroll
  for (int i = 0; i < 4; ++i)
#pragma unroll
    for (int j = 0; j < 4; ++j) {
      double m = (double)acc[i][j] * (1.0 / 256.0);
      tsum -= m * log(m + 1e-10);
    }
  __shared__ double red[256];
  red[tid] = tsum;
  __syncthreads();
  for (int s = 128; s > 0; s >>= 1) {
    if (tid < s) red[tid] += red[tid + s];
    __syncthreads();
  }
  if (tid == 0) mePart[blockIdx.y * 16 + blockIdx.x] = red[0];
}

__global__ __launch_bounds__(256) void lfq_k3_final(
    const double* __restrict__ entPart, const double* __restrict__ comPart,
    const double* __restrict__ mePart, float* __restrict__ out) {
  __shared__ double r1[256], r2[256], r3[256];
  const int tid = threadIdx.x;
  r1[tid] = entPart[tid];
  r2[tid] = comPart[tid];
  r3[tid] = mePart[tid];
  __syncthreads();
  for (int s = 128; s > 0; s >>= 1) {
    if (tid < s) {
      r1[tid] += r1[tid + s];
      r2[tid] += r2[tid + s];
      r3[tid] += r3[tid + s];
    }
    __syncthreads();
  }
  if (tid == 0) {
    double entro_mean_s = r1[0] / 256.0;   // sum_t sum_j H / (B*N)
    double commit = r2[0] / (double)NQ;    // mean over 5120 elems
    double me = r3[0];                     // mean_entro (positive)
    out[NQ + 0] = (float)entro_mean_s;
    out[NQ + 1] = (float)me;
    out[NQ + 2] = (float)(entro_mean_s - me);  // ALPHA=1
    out[NQ + 3] = (float)commit;
  }
}

extern "C" void kernel_launch(void* const* d_in, const int* in_sizes, int n_in,
                              void* d_out, int out_size, void* d_ws, size_t ws_size,
                              hipStream_t stream) {
  const float* x = (const float*)d_in[0];
  float* out = (float*)d_out;
  char* ws = (char*)d_ws;
  float* Hi = (float*)(ws);
  float* Lo = (float*)(ws + (1u << 20));
  double* entPart = (double*)(ws + (2u << 20));
  double* comPart = (double*)(ws + (2u << 20) + 2048);
  double* mePart  = (double*)(ws + (2u << 20) + 4096);

  lfq_k1_pertoken<<<NTOK, 64, 0, stream>>>(x, out, Hi, Lo, entPart, comPart);
  lfq_k2_meanentro<<<dim3(16, 16), 256, 0, stream>>>(Hi, Lo, mePart);
  lfq_k3_final<<<1, 256, 0, stream>>>(entPart, comPart, mePart, out);
}